// Round 3
// baseline (937.843 us; speedup 1.0000x reference)
//
#include <hip/hip_runtime.h>
#include <hip/hip_bf16.h>

// GATModel: 3-layer GAT (heads 4/4/1) + BN/ELU + residual + mean-pool + conv1d head.
// N=50000 nodes, E=800000 edges (+N self-loops handled analytically),
// NODE_DIM=HH=128, HID=32, HEADS=4, B=64 graphs.
//
// Workspace layout (needs ~82.3 MB):
//   deg      [50000 i32]  @ 0
//   psum     [64*32 f32]  @ 200000
//   pcnt     [64 f32]     @ 208192
//   cursor   [50000 i32]  @ 208448
//   offs     [50001 i32]  @ 408448
//   es       [N*4 f32]    @ 608512
//   ed       [N*4 f32]    @ 1408512
//   csr_src  [800000 i32] @ 2208512
//   hA       [N*128 f32]  @ 5408512
//   act0     [N*128 f32]  @ 31008512
//   act1     [N*128 f32]  @ 56608512
// total 82208512 bytes

#define NNODES 50000
#define NEDGES 800000
#define BN_INV 0.9999950000374997f  // 1/sqrt(1+1e-5)

// ---------------- CSR build ----------------

__global__ __launch_bounds__(256) void count_deg(const int* __restrict__ dst,
                                                 int* __restrict__ deg, int E) {
  int i = blockIdx.x * 256 + threadIdx.x;
  if (i < E) atomicAdd(&deg[dst[i]], 1);
}

__global__ __launch_bounds__(1024) void scan_kernel(const int* __restrict__ deg,
    int* __restrict__ offs, int* __restrict__ cursor, int Nn) {
  __shared__ int wsum[16];
  __shared__ int woff[17];
  __shared__ int carry;
  int t = threadIdx.x, lane = t & 63, w = t >> 6;
  if (t == 0) carry = 0;
  __syncthreads();
  for (int base = 0; base < Nn; base += 1024 * 8) {
    int v[8]; int s = 0;
    int i0 = base + t * 8;
#pragma unroll
    for (int j = 0; j < 8; ++j) { int i = i0 + j; v[j] = (i < Nn) ? deg[i] : 0; s += v[j]; }
    int incl = s;
#pragma unroll
    for (int o = 1; o < 64; o <<= 1) { int x = __shfl_up(incl, o); if (lane >= o) incl += x; }
    if (lane == 63) wsum[w] = incl;
    __syncthreads();
    if (t == 0) { int r = carry; for (int i = 0; i < 16; ++i) { woff[i] = r; r += wsum[i]; } woff[16] = r; }
    __syncthreads();
    int run = woff[w] + (incl - s);  // exclusive prefix of this thread's first element
#pragma unroll
    for (int j = 0; j < 8; ++j) {
      int i = i0 + j;
      if (i < Nn) { offs[i] = run; cursor[i] = run; }
      run += v[j];
    }
    __syncthreads();
    if (t == 0) carry = woff[16];
    __syncthreads();
  }
  if (t == 0) offs[Nn] = carry;
}

__global__ __launch_bounds__(256) void fill_csr(const int* __restrict__ src,
    const int* __restrict__ dst, int* __restrict__ cursor,
    int* __restrict__ csr, int E) {
  int i = blockIdx.x * 256 + threadIdx.x;
  if (i < E) {
    int d = dst[i];
    int pos = atomicAdd(&cursor[d], 1);
    csr[pos] = src[i];
  }
}

// ---------------- GEMM: C(N x NC) = A(N x 128) @ W(128 x NC), fp32 ----------------

template <int NC>
__global__ __launch_bounds__(256) void gemm_k128(const float* __restrict__ A,
    const float* __restrict__ W, float* __restrict__ C, int Nrows) {
  constexpr int CG = NC / 4;       // colgroups (4 cols each)
  constexpr int RG = 256 / CG;     // rowgroups
  constexpr int RPT = 32 / RG;     // rows per thread (block tile = 32 rows)
  int cg = threadIdx.x % CG;
  int rg = threadIdx.x / CG;
  int c0 = cg * 4;
  int rbase = blockIdx.x * 32 + rg * RPT;
  float acc[RPT][4];
#pragma unroll
  for (int r = 0; r < RPT; ++r)
#pragma unroll
    for (int j = 0; j < 4; ++j) acc[r][j] = 0.f;
  int rows[RPT];
#pragma unroll
  for (int r = 0; r < RPT; ++r) { int rr = rbase + r; rows[r] = rr < Nrows ? rr : Nrows - 1; }
#pragma unroll 8
  for (int k = 0; k < 128; k += 4) {
    float4 w0 = *(const float4*)&W[(k + 0) * NC + c0];
    float4 w1 = *(const float4*)&W[(k + 1) * NC + c0];
    float4 w2 = *(const float4*)&W[(k + 2) * NC + c0];
    float4 w3 = *(const float4*)&W[(k + 3) * NC + c0];
#pragma unroll
    for (int r = 0; r < RPT; ++r) {
      float4 a = *(const float4*)&A[(size_t)rows[r] * 128 + k];
      acc[r][0] += a.x * w0.x + a.y * w1.x + a.z * w2.x + a.w * w3.x;
      acc[r][1] += a.x * w0.y + a.y * w1.y + a.z * w2.y + a.w * w3.y;
      acc[r][2] += a.x * w0.z + a.y * w1.z + a.z * w2.z + a.w * w3.z;
      acc[r][3] += a.x * w0.w + a.y * w1.w + a.z * w2.w + a.w * w3.w;
    }
  }
#pragma unroll
  for (int r = 0; r < RPT; ++r) {
    int rr = rbase + r;
    if (rr < Nrows)
      *(float4*)&C[(size_t)rr * NC + c0] = make_float4(acc[r][0], acc[r][1], acc[r][2], acc[r][3]);
  }
}

// ---------------- attention coefficients: es/ed[n][head] = sum_o h*a ----------------

template <int HHTOT, int NH>
__global__ __launch_bounds__(256) void attn_coef(const float* __restrict__ h,
    const float* __restrict__ a_s, const float* __restrict__ a_d,
    float* __restrict__ es, float* __restrict__ ed, int Nn) {
  constexpr int NPB = 256 / HHTOT;
  int c = threadIdx.x % HHTOT;
  int n = blockIdx.x * NPB + threadIdx.x / HHTOT;
  if (n >= Nn) return;
  float v = h[(size_t)n * HHTOT + c];
  float ps = v * a_s[c];
  float pd = v * a_d[c];
#pragma unroll
  for (int o = 16; o >= 1; o >>= 1) {
    ps += __shfl_xor(ps, o);
    pd += __shfl_xor(pd, o);
  }
  if ((c & 31) == 0) {
    int head = c >> 5;
    es[n * NH + head] = ps;
    ed[n * NH + head] = pd;
  }
}

// ---------------- GAT aggregation (HH=128, 4 heads) fused bias+res+BN+ELU ----------

template <bool RES>
__global__ __launch_bounds__(128) void gat_agg128(const float* __restrict__ h,
    const float* __restrict__ es, const float* __restrict__ ed,
    const int* __restrict__ offs, const int* __restrict__ csr,
    const float* __restrict__ bias, const float* __restrict__ gamma,
    const float* __restrict__ beta, const float* __restrict__ resid,
    float* __restrict__ out) {
  int n = blockIdx.x;
  int c = threadIdx.x;          // 0..127
  int hh = c >> 5;              // head
  float edn = ed[n * 4 + hh];
  // self loop (softmax is shift-invariant; skip segment_max)
  float e0 = es[n * 4 + hh] + edn;
  e0 = e0 > 0.f ? e0 : 0.2f * e0;
  float w0 = __expf(e0);
  float den = w0;
  float acc = w0 * h[(size_t)n * 128 + c];
  int beg = offs[n], end = offs[n + 1];
  for (int j = beg; j < end; ++j) {
    int s = csr[j];
    float e = es[s * 4 + hh] + edn;
    e = e > 0.f ? e : 0.2f * e;
    float w = __expf(e);
    den += w;
    acc += w * h[(size_t)s * 128 + c];
  }
  float val = acc / (den + 1e-16f) + bias[c];
  if (RES) val += resid[(size_t)n * 128 + c];
  val = gamma[c] * val * BN_INV + beta[c];
  out[(size_t)n * 128 + c] = val > 0.f ? val : __expf(val) - 1.f;
}

// ---------------- layer-2 aggregation (H=1, O=32) fused with graph pooling --------

__global__ __launch_bounds__(256) void gat_agg32_pool(const float* __restrict__ h,
    const float* __restrict__ es, const float* __restrict__ ed,
    const int* __restrict__ offs, const int* __restrict__ csr,
    const float* __restrict__ bias, const int* __restrict__ batch,
    float* __restrict__ psum, float* __restrict__ pcnt, int Nn) {
  int n = blockIdx.x * 8 + (threadIdx.x >> 5);
  if (n >= Nn) return;
  int c = threadIdx.x & 31;
  float edn = ed[n];
  float e0 = es[n] + edn;
  e0 = e0 > 0.f ? e0 : 0.2f * e0;
  float w0 = __expf(e0);
  float den = w0;
  float acc = w0 * h[(size_t)n * 32 + c];
  int beg = offs[n], end = offs[n + 1];
  for (int j = beg; j < end; ++j) {
    int s = csr[j];
    float e = es[s] + edn;
    e = e > 0.f ? e : 0.2f * e;
    float w = __expf(e);
    den += w;
    acc += w * h[(size_t)s * 32 + c];
  }
  float val = acc / (den + 1e-16f) + bias[c];
  int b = batch[n];
  atomicAdd(&psum[b * 32 + c], val);
  if (c == 0) atomicAdd(&pcnt[b], 1.0f);
}

// ---------------- head: pool-mean, conv1d x2, MLP, log_softmax (1 block/graph) ----

__global__ __launch_bounds__(256) void head_kernel(const float* __restrict__ psum,
    const float* __restrict__ pcnt,
    const float* __restrict__ c0w, const float* __restrict__ c0b,
    const float* __restrict__ cg0, const float* __restrict__ cb0,
    const float* __restrict__ c1w, const float* __restrict__ c1b,
    const float* __restrict__ l1w, const float* __restrict__ l1b,
    const float* __restrict__ l2w, const float* __restrict__ l2b,
    float* __restrict__ out) {
  int b = blockIdx.x;
  int t = threadIdx.x;
  __shared__ float pooled[32];
  __shared__ float z1[32][32];   // [oc][t]
  __shared__ float z2[16][32];
  __shared__ float emb[16];
  __shared__ float hfc[8];
  __shared__ float logits[10];
  if (t < 32) {
    float cn = fmaxf(pcnt[b], 1.0f);
    pooled[t] = psum[b * 32 + t] / cn;
  }
  __syncthreads();
  // conv1: in (1,32) -> out (32,32), kernel 5, pad 2; + bias, BN, ELU
  for (int i = t; i < 1024; i += 256) {
    int oc = i >> 5, tt = i & 31;
    float a = c0b[oc];
#pragma unroll
    for (int k = 0; k < 5; ++k) {
      int p = tt + k - 2;
      if (p >= 0 && p < 32) a += pooled[p] * c0w[oc * 5 + k];
    }
    a = cg0[oc] * a * BN_INV + cb0[oc];
    z1[oc][tt] = a > 0.f ? a : __expf(a) - 1.f;
  }
  __syncthreads();
  // conv2: in (32,32) -> out (16,32), kernel 5, pad 2; + bias
  for (int i = t; i < 512; i += 256) {
    int oc = i >> 5, tt = i & 31;
    float a = c1b[oc];
    for (int ic = 0; ic < 32; ++ic) {
      const float* wrow = &c1w[(oc * 32 + ic) * 5];
#pragma unroll
      for (int k = 0; k < 5; ++k) {
        int p = tt + k - 2;
        if (p >= 0 && p < 32) a += z1[ic][p] * wrow[k];
      }
    }
    z2[oc][tt] = a;
  }
  __syncthreads();
  if (t < 16) {
    float s = 0.f;
    for (int i = 0; i < 32; ++i) s += z2[t][i];
    s *= (1.0f / 32.0f);
    emb[t] = s;
    out[640 + b * 16 + t] = s;     // output 1: embed (64 x 16)
  }
  __syncthreads();
  if (t < 8) {
    float a = l1b[t];
    for (int i = 0; i < 16; ++i) a += emb[i] * l1w[i * 8 + t];
    hfc[t] = a > 0.f ? a : __expf(a) - 1.f;
  }
  __syncthreads();
  if (t < 10) {
    float a = l2b[t];
    for (int j = 0; j < 8; ++j) a += hfc[j] * l2w[j * 10 + t];
    logits[t] = a;
  }
  __syncthreads();
  if (t == 0) {
    float m = logits[0];
    for (int k = 1; k < 10; ++k) m = fmaxf(m, logits[k]);
    float s = 0.f;
    for (int k = 0; k < 10; ++k) s += __expf(logits[k] - m);
    float lse = m + logf(s);
    for (int k = 0; k < 10; ++k) out[b * 10 + k] = logits[k] - lse;  // output 0
  }
}

// ---------------- launch ----------------

extern "C" void kernel_launch(void* const* d_in, const int* in_sizes, int n_in,
                              void* d_out, int out_size, void* d_ws, size_t ws_size,
                              hipStream_t stream) {
  const float* x   = (const float*)d_in[0];
  const int* eidx  = (const int*)d_in[1];
  const int* esrc  = eidx;
  const int* edst  = eidx + NEDGES;
  const int* batch = (const int*)d_in[2];
  const float* W0  = (const float*)d_in[3];
  const float* a0s = (const float*)d_in[4];
  const float* a0d = (const float*)d_in[5];
  const float* b0  = (const float*)d_in[6];
  const float* W1  = (const float*)d_in[7];
  const float* a1s = (const float*)d_in[8];
  const float* a1d = (const float*)d_in[9];
  const float* b1  = (const float*)d_in[10];
  const float* W2  = (const float*)d_in[11];
  const float* a2s = (const float*)d_in[12];
  const float* a2d = (const float*)d_in[13];
  const float* b2  = (const float*)d_in[14];
  const float* g0  = (const float*)d_in[15];
  const float* be0 = (const float*)d_in[16];
  const float* g1  = (const float*)d_in[17];
  const float* be1 = (const float*)d_in[18];
  const float* c0w = (const float*)d_in[19];
  const float* c0b = (const float*)d_in[20];
  const float* cg0 = (const float*)d_in[21];
  const float* cb0 = (const float*)d_in[22];
  const float* c1w = (const float*)d_in[23];
  const float* c1b = (const float*)d_in[24];
  const float* l1w = (const float*)d_in[25];
  const float* l1b = (const float*)d_in[26];
  const float* l2w = (const float*)d_in[27];
  const float* l2b = (const float*)d_in[28];

  char* ws = (char*)d_ws;
  int*   deg    = (int*)(ws + 0);
  float* psum   = (float*)(ws + 200000);
  float* pcnt   = (float*)(ws + 208192);
  int*   cursor = (int*)(ws + 208448);
  int*   offs   = (int*)(ws + 408448);
  float* es     = (float*)(ws + 608512);
  float* ed     = (float*)(ws + 1408512);
  int*   csr    = (int*)(ws + 2208512);
  float* hA     = (float*)(ws + 5408512);
  float* act0   = (float*)(ws + 31008512);
  float* act1   = (float*)(ws + 56608512);
  float* out    = (float*)d_out;

  // zero deg + psum + pcnt (contiguous prefix of ws)
  hipMemsetAsync(d_ws, 0, 208448, stream);

  // CSR build (real edges only; self-loops handled in-kernel)
  count_deg<<<(NEDGES + 255) / 256, 256, 0, stream>>>(edst, deg, NEDGES);
  scan_kernel<<<1, 1024, 0, stream>>>(deg, offs, cursor, NNODES);
  fill_csr<<<(NEDGES + 255) / 256, 256, 0, stream>>>(esrc, edst, cursor, csr, NEDGES);

  const int gemm_grid = (NNODES + 31) / 32;

  // --- layer 0 ---
  gemm_k128<128><<<gemm_grid, 256, 0, stream>>>(x, W0, hA, NNODES);
  attn_coef<128, 4><<<NNODES / 2, 256, 0, stream>>>(hA, a0s, a0d, es, ed, NNODES);
  gat_agg128<false><<<NNODES, 128, 0, stream>>>(hA, es, ed, offs, csr, b0, g0, be0, nullptr, act0);

  // --- layer 1 (residual) ---
  gemm_k128<128><<<gemm_grid, 256, 0, stream>>>(act0, W1, hA, NNODES);
  attn_coef<128, 4><<<NNODES / 2, 256, 0, stream>>>(hA, a1s, a1d, es, ed, NNODES);
  gat_agg128<true><<<NNODES, 128, 0, stream>>>(hA, es, ed, offs, csr, b1, g1, be1, act0, act1);

  // --- layer 2 (H=1, O=32) + pooling ---
  gemm_k128<32><<<gemm_grid, 256, 0, stream>>>(act1, W2, hA, NNODES);
  attn_coef<32, 1><<<NNODES / 8, 256, 0, stream>>>(hA, a2s, a2d, es, ed, NNODES);
  gat_agg32_pool<<<NNODES / 8, 256, 0, stream>>>(hA, es, ed, offs, csr, b2, batch, psum, pcnt, NNODES);

  // --- head ---
  head_kernel<<<64, 256, 0, stream>>>(psum, pcnt, c0w, c0b, cg0, cb0,
                                      c1w, c1b, l1w, l1b, l2w, l2b, out);
}

// Round 4
// 620.080 us; speedup vs baseline: 1.5125x; 1.5125x over previous
//
#include <hip/hip_runtime.h>
#include <hip/hip_bf16.h>

// GATModel: 3-layer GAT (heads 4/4/1) + BN/ELU + residual + mean-pool + conv1d head.
// N=50000 nodes, E=800000 edges (+N self-loops handled analytically),
// NODE_DIM=HH=128, HID=32, HEADS=4, B=64 graphs.
//
// R3 changes vs R2:
//  - gat_agg32_pool atomics removed (was 420us, 45% of total: 1.6M same-line
//    device atomics, cross-XCD serialization). Now writes per-node h2; pooling
//    fused into head_kernel via sorted-batch binary search + LDS reduce.
//  - attn_coef kernels fused into GEMM epilogue (8-lane shfl reduce of
//    in-register accumulators) — removes 3 dispatches + ~58MB of hA re-reads.
//
// Workspace layout (~82.3 MB):
//   deg      [50000 i32]  @ 0
//   (unused) [..]         @ 200000
//   cursor   [50000 i32]  @ 208448
//   offs     [50001 i32]  @ 408448
//   es       [N*4 f32]    @ 608512
//   ed       [N*4 f32]    @ 1408512
//   csr_src  [800000 i32] @ 2208512
//   hA       [N*128 f32]  @ 5408512
//   act0     [N*128 f32]  @ 31008512   (also reused as h2 [N*32] after free)
//   act1     [N*128 f32]  @ 56608512

#define NNODES 50000
#define NEDGES 800000
#define BN_INV 0.9999950000374997f  // 1/sqrt(1+1e-5)

// ---------------- CSR build ----------------

__global__ __launch_bounds__(256) void count_deg(const int* __restrict__ dst,
                                                 int* __restrict__ deg, int E) {
  int i = blockIdx.x * 256 + threadIdx.x;
  if (i < E) atomicAdd(&deg[dst[i]], 1);
}

__global__ __launch_bounds__(1024) void scan_kernel(const int* __restrict__ deg,
    int* __restrict__ offs, int* __restrict__ cursor, int Nn) {
  __shared__ int wsum[16];
  __shared__ int woff[17];
  __shared__ int carry;
  int t = threadIdx.x, lane = t & 63, w = t >> 6;
  if (t == 0) carry = 0;
  __syncthreads();
  for (int base = 0; base < Nn; base += 1024 * 8) {
    int v[8]; int s = 0;
    int i0 = base + t * 8;
#pragma unroll
    for (int j = 0; j < 8; ++j) { int i = i0 + j; v[j] = (i < Nn) ? deg[i] : 0; s += v[j]; }
    int incl = s;
#pragma unroll
    for (int o = 1; o < 64; o <<= 1) { int x = __shfl_up(incl, o); if (lane >= o) incl += x; }
    if (lane == 63) wsum[w] = incl;
    __syncthreads();
    if (t == 0) { int r = carry; for (int i = 0; i < 16; ++i) { woff[i] = r; r += wsum[i]; } woff[16] = r; }
    __syncthreads();
    int run = woff[w] + (incl - s);
#pragma unroll
    for (int j = 0; j < 8; ++j) {
      int i = i0 + j;
      if (i < Nn) { offs[i] = run; cursor[i] = run; }
      run += v[j];
    }
    __syncthreads();
    if (t == 0) carry = woff[16];
    __syncthreads();
  }
  if (t == 0) offs[Nn] = carry;
}

__global__ __launch_bounds__(256) void fill_csr(const int* __restrict__ src,
    const int* __restrict__ dst, int* __restrict__ cursor,
    int* __restrict__ csr, int E) {
  int i = blockIdx.x * 256 + threadIdx.x;
  if (i < E) {
    int d = dst[i];
    int pos = atomicAdd(&cursor[d], 1);
    csr[pos] = src[i];
  }
}

// ------- GEMM: C(N x NC) = A(N x 128) @ W(128 x NC), fp32, fused attn coefs -------
// es[n][h] = sum_c h[n][c]*a_s[c] over head h's 32 channels (NH=4) or all 32 (NH=1).
// A row's NC/4 colgroups live in consecutive lanes -> 8-lane shfl_xor reduce.

template <int NC, int NH>
__global__ __launch_bounds__(256) void gemm_attn(const float* __restrict__ A,
    const float* __restrict__ W, const float* __restrict__ a_s,
    const float* __restrict__ a_d, float* __restrict__ C,
    float* __restrict__ es, float* __restrict__ ed, int Nrows) {
  constexpr int CG = NC / 4;       // colgroups (4 cols each)
  constexpr int RG = 256 / CG;     // rowgroups
  constexpr int RPT = 32 / RG;     // rows per thread (block tile = 32 rows)
  int cg = threadIdx.x % CG;
  int rg = threadIdx.x / CG;
  int c0 = cg * 4;
  int rbase = blockIdx.x * 32 + rg * RPT;
  float acc[RPT][4];
#pragma unroll
  for (int r = 0; r < RPT; ++r)
#pragma unroll
    for (int j = 0; j < 4; ++j) acc[r][j] = 0.f;
  int rows[RPT];
#pragma unroll
  for (int r = 0; r < RPT; ++r) { int rr = rbase + r; rows[r] = rr < Nrows ? rr : Nrows - 1; }
#pragma unroll 8
  for (int k = 0; k < 128; k += 4) {
    float4 w0 = *(const float4*)&W[(k + 0) * NC + c0];
    float4 w1 = *(const float4*)&W[(k + 1) * NC + c0];
    float4 w2 = *(const float4*)&W[(k + 2) * NC + c0];
    float4 w3 = *(const float4*)&W[(k + 3) * NC + c0];
#pragma unroll
    for (int r = 0; r < RPT; ++r) {
      float4 a = *(const float4*)&A[(size_t)rows[r] * 128 + k];
      acc[r][0] += a.x * w0.x + a.y * w1.x + a.z * w2.x + a.w * w3.x;
      acc[r][1] += a.x * w0.y + a.y * w1.y + a.z * w2.y + a.w * w3.y;
      acc[r][2] += a.x * w0.z + a.y * w1.z + a.z * w2.z + a.w * w3.z;
      acc[r][3] += a.x * w0.w + a.y * w1.w + a.z * w2.w + a.w * w3.w;
    }
  }
  float4 as4 = *(const float4*)&a_s[c0];
  float4 ad4 = *(const float4*)&a_d[c0];
#pragma unroll
  for (int r = 0; r < RPT; ++r) {
    int rr = rbase + r;
    if (rr < Nrows)
      *(float4*)&C[(size_t)rr * NC + c0] = make_float4(acc[r][0], acc[r][1], acc[r][2], acc[r][3]);
    // fused attention coefficients: reduce over the 8 lanes covering one head
    float ps = acc[r][0] * as4.x + acc[r][1] * as4.y + acc[r][2] * as4.z + acc[r][3] * as4.w;
    float pd = acc[r][0] * ad4.x + acc[r][1] * ad4.y + acc[r][2] * ad4.z + acc[r][3] * ad4.w;
#pragma unroll
    for (int o = 1; o < 8; o <<= 1) {
      ps += __shfl_xor(ps, o);
      pd += __shfl_xor(pd, o);
    }
    if ((cg & 7) == 0 && rr < Nrows) {
      int hh = cg >> 3;  // head index (0..NH-1); for NC=32 (NH=1) cg==0 -> hh==0
      es[rr * NH + hh] = ps;
      ed[rr * NH + hh] = pd;
    }
  }
}

// ---------------- GAT aggregation (HH=128, 4 heads) fused bias+res+BN+ELU ----------

template <bool RES>
__global__ __launch_bounds__(128) void gat_agg128(const float* __restrict__ h,
    const float* __restrict__ es, const float* __restrict__ ed,
    const int* __restrict__ offs, const int* __restrict__ csr,
    const float* __restrict__ bias, const float* __restrict__ gamma,
    const float* __restrict__ beta, const float* __restrict__ resid,
    float* __restrict__ out) {
  int n = blockIdx.x;
  int c = threadIdx.x;          // 0..127
  int hh = c >> 5;              // head
  float edn = ed[n * 4 + hh];
  // self loop (softmax is shift-invariant; skip segment_max)
  float e0 = es[n * 4 + hh] + edn;
  e0 = e0 > 0.f ? e0 : 0.2f * e0;
  float w0 = __expf(e0);
  float den = w0;
  float acc = w0 * h[(size_t)n * 128 + c];
  int beg = offs[n], end = offs[n + 1];
  for (int j = beg; j < end; ++j) {
    int s = csr[j];
    float e = es[s * 4 + hh] + edn;
    e = e > 0.f ? e : 0.2f * e;
    float w = __expf(e);
    den += w;
    acc += w * h[(size_t)s * 128 + c];
  }
  float val = acc / (den + 1e-16f) + bias[c];
  if (RES) val += resid[(size_t)n * 128 + c];
  val = gamma[c] * val * BN_INV + beta[c];
  out[(size_t)n * 128 + c] = val > 0.f ? val : __expf(val) - 1.f;
}

// ---------------- layer-2 aggregation (H=1, O=32), no atomics ----------------

__global__ __launch_bounds__(256) void gat_agg32(const float* __restrict__ h,
    const float* __restrict__ es, const float* __restrict__ ed,
    const int* __restrict__ offs, const int* __restrict__ csr,
    const float* __restrict__ bias, float* __restrict__ h2, int Nn) {
  int n = blockIdx.x * 8 + (threadIdx.x >> 5);
  if (n >= Nn) return;
  int c = threadIdx.x & 31;
  float edn = ed[n];
  float e0 = es[n] + edn;
  e0 = e0 > 0.f ? e0 : 0.2f * e0;
  float w0 = __expf(e0);
  float den = w0;
  float acc = w0 * h[(size_t)n * 32 + c];
  int beg = offs[n], end = offs[n + 1];
  for (int j = beg; j < end; ++j) {
    int s = csr[j];
    float e = es[s] + edn;
    e = e > 0.f ? e : 0.2f * e;
    float w = __expf(e);
    den += w;
    acc += w * h[(size_t)s * 32 + c];
  }
  h2[(size_t)n * 32 + c] = acc / (den + 1e-16f) + bias[c];
}

// -------- head: mean-pool (sorted-batch range), conv1d x2, MLP, log_softmax -------
// One block per graph. batch is sorted -> binary search the node range; no atomics.

__global__ __launch_bounds__(256) void head_kernel(const float* __restrict__ h2,
    const int* __restrict__ batch,
    const float* __restrict__ c0w, const float* __restrict__ c0b,
    const float* __restrict__ cg0, const float* __restrict__ cb0,
    const float* __restrict__ c1w, const float* __restrict__ c1b,
    const float* __restrict__ l1w, const float* __restrict__ l1b,
    const float* __restrict__ l2w, const float* __restrict__ l2b,
    float* __restrict__ out) {
  int b = blockIdx.x;
  int t = threadIdx.x;
  __shared__ float sums[8][32];
  __shared__ float pooled[32];
  __shared__ float z1[32][32];   // [oc][t]
  __shared__ float z2[16][32];
  __shared__ float emb[16];
  __shared__ float hfc[8];
  __shared__ float logits[10];

  // range of graph b in sorted batch
  int lo = 0, hi = NNODES;
  while (lo < hi) { int mid = (lo + hi) >> 1; if (batch[mid] < b) lo = mid + 1; else hi = mid; }
  int start = lo;
  lo = 0; hi = NNODES;
  while (lo < hi) { int mid = (lo + hi) >> 1; if (batch[mid] < b + 1) lo = mid + 1; else hi = mid; }
  int end = lo;

  // strided accumulate: thread t covers channel t&31, rows start+(t>>5), stride 8
  {
    int ch = t & 31, g = t >> 5;
    float s = 0.f;
    for (int i = start + g; i < end; i += 8) s += h2[(size_t)i * 32 + ch];
    sums[g][ch] = s;
  }
  __syncthreads();
  if (t < 32) {
    float s = 0.f;
#pragma unroll
    for (int g = 0; g < 8; ++g) s += sums[g][t];
    float cn = fmaxf((float)(end - start), 1.0f);
    pooled[t] = s / cn;
  }
  __syncthreads();
  // conv1: in (1,32) -> out (32,32), kernel 5, pad 2; + bias, BN, ELU
  for (int i = t; i < 1024; i += 256) {
    int oc = i >> 5, tt = i & 31;
    float a = c0b[oc];
#pragma unroll
    for (int k = 0; k < 5; ++k) {
      int p = tt + k - 2;
      if (p >= 0 && p < 32) a += pooled[p] * c0w[oc * 5 + k];
    }
    a = cg0[oc] * a * BN_INV + cb0[oc];
    z1[oc][tt] = a > 0.f ? a : __expf(a) - 1.f;
  }
  __syncthreads();
  // conv2: in (32,32) -> out (16,32), kernel 5, pad 2; + bias
  for (int i = t; i < 512; i += 256) {
    int oc = i >> 5, tt = i & 31;
    float a = c1b[oc];
    for (int ic = 0; ic < 32; ++ic) {
      const float* wrow = &c1w[(oc * 32 + ic) * 5];
#pragma unroll
      for (int k = 0; k < 5; ++k) {
        int p = tt + k - 2;
        if (p >= 0 && p < 32) a += z1[ic][p] * wrow[k];
      }
    }
    z2[oc][tt] = a;
  }
  __syncthreads();
  if (t < 16) {
    float s = 0.f;
    for (int i = 0; i < 32; ++i) s += z2[t][i];
    s *= (1.0f / 32.0f);
    emb[t] = s;
    out[640 + b * 16 + t] = s;     // output 1: embed (64 x 16)
  }
  __syncthreads();
  if (t < 8) {
    float a = l1b[t];
    for (int i = 0; i < 16; ++i) a += emb[i] * l1w[i * 8 + t];
    hfc[t] = a > 0.f ? a : __expf(a) - 1.f;
  }
  __syncthreads();
  if (t < 10) {
    float a = l2b[t];
    for (int j = 0; j < 8; ++j) a += hfc[j] * l2w[j * 10 + t];
    logits[t] = a;
  }
  __syncthreads();
  if (t == 0) {
    float m = logits[0];
    for (int k = 1; k < 10; ++k) m = fmaxf(m, logits[k]);
    float s = 0.f;
    for (int k = 0; k < 10; ++k) s += __expf(logits[k] - m);
    float lse = m + logf(s);
    for (int k = 0; k < 10; ++k) out[b * 10 + k] = logits[k] - lse;  // output 0
  }
}

// ---------------- launch ----------------

extern "C" void kernel_launch(void* const* d_in, const int* in_sizes, int n_in,
                              void* d_out, int out_size, void* d_ws, size_t ws_size,
                              hipStream_t stream) {
  const float* x   = (const float*)d_in[0];
  const int* eidx  = (const int*)d_in[1];
  const int* esrc  = eidx;
  const int* edst  = eidx + NEDGES;
  const int* batch = (const int*)d_in[2];
  const float* W0  = (const float*)d_in[3];
  const float* a0s = (const float*)d_in[4];
  const float* a0d = (const float*)d_in[5];
  const float* b0  = (const float*)d_in[6];
  const float* W1  = (const float*)d_in[7];
  const float* a1s = (const float*)d_in[8];
  const float* a1d = (const float*)d_in[9];
  const float* b1  = (const float*)d_in[10];
  const float* W2  = (const float*)d_in[11];
  const float* a2s = (const float*)d_in[12];
  const float* a2d = (const float*)d_in[13];
  const float* b2  = (const float*)d_in[14];
  const float* g0  = (const float*)d_in[15];
  const float* be0 = (const float*)d_in[16];
  const float* g1  = (const float*)d_in[17];
  const float* be1 = (const float*)d_in[18];
  const float* c0w = (const float*)d_in[19];
  const float* c0b = (const float*)d_in[20];
  const float* cg0 = (const float*)d_in[21];
  const float* cb0 = (const float*)d_in[22];
  const float* c1w = (const float*)d_in[23];
  const float* c1b = (const float*)d_in[24];
  const float* l1w = (const float*)d_in[25];
  const float* l1b = (const float*)d_in[26];
  const float* l2w = (const float*)d_in[27];
  const float* l2b = (const float*)d_in[28];

  char* ws = (char*)d_ws;
  int*   deg    = (int*)(ws + 0);
  int*   cursor = (int*)(ws + 208448);
  int*   offs   = (int*)(ws + 408448);
  float* es     = (float*)(ws + 608512);
  float* ed     = (float*)(ws + 1408512);
  int*   csr    = (int*)(ws + 2208512);
  float* hA     = (float*)(ws + 5408512);
  float* act0   = (float*)(ws + 31008512);
  float* act1   = (float*)(ws + 56608512);
  float* h2     = act0;              // act0 free after layer-1 agg
  float* out    = (float*)d_out;

  // zero deg
  hipMemsetAsync(d_ws, 0, 200000, stream);

  // CSR build (real edges only; self-loops handled in-kernel)
  count_deg<<<(NEDGES + 255) / 256, 256, 0, stream>>>(edst, deg, NEDGES);
  scan_kernel<<<1, 1024, 0, stream>>>(deg, offs, cursor, NNODES);
  fill_csr<<<(NEDGES + 255) / 256, 256, 0, stream>>>(esrc, edst, cursor, csr, NEDGES);

  const int gemm_grid = (NNODES + 31) / 32;

  // --- layer 0 ---
  gemm_attn<128, 4><<<gemm_grid, 256, 0, stream>>>(x, W0, a0s, a0d, hA, es, ed, NNODES);
  gat_agg128<false><<<NNODES, 128, 0, stream>>>(hA, es, ed, offs, csr, b0, g0, be0, nullptr, act0);

  // --- layer 1 (residual) ---
  gemm_attn<128, 4><<<gemm_grid, 256, 0, stream>>>(act0, W1, a1s, a1d, hA, es, ed, NNODES);
  gat_agg128<true><<<NNODES, 128, 0, stream>>>(hA, es, ed, offs, csr, b1, g1, be1, act0, act1);

  // --- layer 2 (H=1, O=32), no atomics ---
  gemm_attn<32, 1><<<gemm_grid, 256, 0, stream>>>(act1, W2, a2s, a2d, hA, es, ed, NNODES);
  gat_agg32<<<NNODES / 8, 256, 0, stream>>>(hA, es, ed, offs, csr, b2, h2, NNODES);

  // --- head (pool fused) ---
  head_kernel<<<64, 256, 0, stream>>>(h2, batch, c0w, c0b, cg0, cb0,
                                      c1w, c1b, l1w, l1b, l2w, l2b, out);
}

// Round 5
// 561.123 us; speedup vs baseline: 1.6714x; 1.1051x over previous
//
#include <hip/hip_runtime.h>
#include <hip/hip_bf16.h>

// GATModel: 3-layer GAT (heads 4/4/1) + BN/ELU + residual + mean-pool + conv1d head.
// N=50000 nodes, E=800000 edges (+N self-loops handled analytically),
// NODE_DIM=HH=128, HID=32, HEADS=4, B=64 graphs.
//
// R4 changes vs R3 (gat_agg128 was 103us x2, latency-bound: VALU 39%, hbm 29%,
// dependent csr->h chain, avg deg 16):
//  - 8-edge chunked gather: issue 8 independent h-row + es loads per chunk
//    (breaks the serial latency chain, ~8x MLP).
//  - gat_agg128: one wave per node (lane owns 2 channels, float2), 4 nodes per
//    256-block -> 2x nodes in flight, no duplicated es/exp work across waves.
//
// Workspace layout (~82.3 MB):
//   deg      [50000 i32]  @ 0
//   cursor   [50000 i32]  @ 208448
//   offs     [50001 i32]  @ 408448
//   es       [N*4 f32]    @ 608512
//   ed       [N*4 f32]    @ 1408512
//   csr_src  [800000 i32] @ 2208512
//   hA       [N*128 f32]  @ 5408512
//   act0     [N*128 f32]  @ 31008512   (reused as h2 [N*32] after free)
//   act1     [N*128 f32]  @ 56608512

#define NNODES 50000
#define NEDGES 800000
#define BN_INV 0.9999950000374997f  // 1/sqrt(1+1e-5)

// ---------------- CSR build ----------------

__global__ __launch_bounds__(256) void count_deg(const int* __restrict__ dst,
                                                 int* __restrict__ deg, int E) {
  int i = blockIdx.x * 256 + threadIdx.x;
  if (i < E) atomicAdd(&deg[dst[i]], 1);
}

__global__ __launch_bounds__(1024) void scan_kernel(const int* __restrict__ deg,
    int* __restrict__ offs, int* __restrict__ cursor, int Nn) {
  __shared__ int wsum[16];
  __shared__ int woff[17];
  __shared__ int carry;
  int t = threadIdx.x, lane = t & 63, w = t >> 6;
  if (t == 0) carry = 0;
  __syncthreads();
  for (int base = 0; base < Nn; base += 1024 * 8) {
    int v[8]; int s = 0;
    int i0 = base + t * 8;
#pragma unroll
    for (int j = 0; j < 8; ++j) { int i = i0 + j; v[j] = (i < Nn) ? deg[i] : 0; s += v[j]; }
    int incl = s;
#pragma unroll
    for (int o = 1; o < 64; o <<= 1) { int x = __shfl_up(incl, o); if (lane >= o) incl += x; }
    if (lane == 63) wsum[w] = incl;
    __syncthreads();
    if (t == 0) { int r = carry; for (int i = 0; i < 16; ++i) { woff[i] = r; r += wsum[i]; } woff[16] = r; }
    __syncthreads();
    int run = woff[w] + (incl - s);
#pragma unroll
    for (int j = 0; j < 8; ++j) {
      int i = i0 + j;
      if (i < Nn) { offs[i] = run; cursor[i] = run; }
      run += v[j];
    }
    __syncthreads();
    if (t == 0) carry = woff[16];
    __syncthreads();
  }
  if (t == 0) offs[Nn] = carry;
}

__global__ __launch_bounds__(256) void fill_csr(const int* __restrict__ src,
    const int* __restrict__ dst, int* __restrict__ cursor,
    int* __restrict__ csr, int E) {
  int i = blockIdx.x * 256 + threadIdx.x;
  if (i < E) {
    int d = dst[i];
    int pos = atomicAdd(&cursor[d], 1);
    csr[pos] = src[i];
  }
}

// ------- GEMM: C(N x NC) = A(N x 128) @ W(128 x NC), fp32, fused attn coefs -------

template <int NC, int NH>
__global__ __launch_bounds__(256) void gemm_attn(const float* __restrict__ A,
    const float* __restrict__ W, const float* __restrict__ a_s,
    const float* __restrict__ a_d, float* __restrict__ C,
    float* __restrict__ es, float* __restrict__ ed, int Nrows) {
  constexpr int CG = NC / 4;       // colgroups (4 cols each)
  constexpr int RG = 256 / CG;     // rowgroups
  constexpr int RPT = 32 / RG;     // rows per thread (block tile = 32 rows)
  int cg = threadIdx.x % CG;
  int rg = threadIdx.x / CG;
  int c0 = cg * 4;
  int rbase = blockIdx.x * 32 + rg * RPT;
  float acc[RPT][4];
#pragma unroll
  for (int r = 0; r < RPT; ++r)
#pragma unroll
    for (int j = 0; j < 4; ++j) acc[r][j] = 0.f;
  int rows[RPT];
#pragma unroll
  for (int r = 0; r < RPT; ++r) { int rr = rbase + r; rows[r] = rr < Nrows ? rr : Nrows - 1; }
#pragma unroll 8
  for (int k = 0; k < 128; k += 4) {
    float4 w0 = *(const float4*)&W[(k + 0) * NC + c0];
    float4 w1 = *(const float4*)&W[(k + 1) * NC + c0];
    float4 w2 = *(const float4*)&W[(k + 2) * NC + c0];
    float4 w3 = *(const float4*)&W[(k + 3) * NC + c0];
#pragma unroll
    for (int r = 0; r < RPT; ++r) {
      float4 a = *(const float4*)&A[(size_t)rows[r] * 128 + k];
      acc[r][0] += a.x * w0.x + a.y * w1.x + a.z * w2.x + a.w * w3.x;
      acc[r][1] += a.x * w0.y + a.y * w1.y + a.z * w2.y + a.w * w3.y;
      acc[r][2] += a.x * w0.z + a.y * w1.z + a.z * w2.z + a.w * w3.z;
      acc[r][3] += a.x * w0.w + a.y * w1.w + a.z * w2.w + a.w * w3.w;
    }
  }
  float4 as4 = *(const float4*)&a_s[c0];
  float4 ad4 = *(const float4*)&a_d[c0];
#pragma unroll
  for (int r = 0; r < RPT; ++r) {
    int rr = rbase + r;
    if (rr < Nrows)
      *(float4*)&C[(size_t)rr * NC + c0] = make_float4(acc[r][0], acc[r][1], acc[r][2], acc[r][3]);
    float ps = acc[r][0] * as4.x + acc[r][1] * as4.y + acc[r][2] * as4.z + acc[r][3] * as4.w;
    float pd = acc[r][0] * ad4.x + acc[r][1] * ad4.y + acc[r][2] * ad4.z + acc[r][3] * ad4.w;
#pragma unroll
    for (int o = 1; o < 8; o <<= 1) {
      ps += __shfl_xor(ps, o);
      pd += __shfl_xor(pd, o);
    }
    if ((cg & 7) == 0 && rr < Nrows) {
      int hh = cg >> 3;
      es[rr * NH + hh] = ps;
      ed[rr * NH + hh] = pd;
    }
  }
}

// ------- GAT aggregation (HH=128, 4 heads), wave-per-node, 8-edge MLP chunks ------
// Block = 256 threads = 4 waves = 4 nodes. Lane l owns channels {2l, 2l+1} (float2).
// head(l) = (2l)>>5 = l>>4.

template <bool RES>
__global__ __launch_bounds__(256) void gat_agg128(const float* __restrict__ h,
    const float* __restrict__ es, const float* __restrict__ ed,
    const int* __restrict__ offs, const int* __restrict__ csr,
    const float* __restrict__ bias, const float* __restrict__ gamma,
    const float* __restrict__ beta, const float* __restrict__ resid,
    float* __restrict__ out, int Nn) {
  int n = blockIdx.x * 4 + (threadIdx.x >> 6);
  if (n >= Nn) return;
  int l = threadIdx.x & 63;
  int c0 = 2 * l;
  int hh = l >> 4;
  float edn = ed[n * 4 + hh];
  // self loop (softmax is shift-invariant; skip segment_max)
  float e0 = es[n * 4 + hh] + edn;
  e0 = e0 > 0.f ? e0 : 0.2f * e0;
  float w0 = __expf(e0);
  float den = w0;
  float2 hself = *(const float2*)&h[(size_t)n * 128 + c0];
  float accx = w0 * hself.x, accy = w0 * hself.y;
  int beg = offs[n], end = offs[n + 1];
  for (int base = beg; base < end; base += 8) {
    int cnt = end - base;  // >=1
    int s[8];
#pragma unroll
    for (int j = 0; j < 8; ++j) s[j] = (j < cnt) ? csr[base + j] : n;
    float2 hv[8];
#pragma unroll
    for (int j = 0; j < 8; ++j) hv[j] = *(const float2*)&h[(size_t)s[j] * 128 + c0];
    float w[8];
#pragma unroll
    for (int j = 0; j < 8; ++j) {
      float e = es[s[j] * 4 + hh] + edn;
      e = e > 0.f ? e : 0.2f * e;
      w[j] = (j < cnt) ? __expf(e) : 0.f;
    }
#pragma unroll
    for (int j = 0; j < 8; ++j) {
      den += w[j];
      accx += w[j] * hv[j].x;
      accy += w[j] * hv[j].y;
    }
  }
  float inv = 1.0f / (den + 1e-16f);
  float2 bi = *(const float2*)&bias[c0];
  float2 ga = *(const float2*)&gamma[c0];
  float2 be = *(const float2*)&beta[c0];
  float vx = accx * inv + bi.x;
  float vy = accy * inv + bi.y;
  if (RES) {
    float2 rv = *(const float2*)&resid[(size_t)n * 128 + c0];
    vx += rv.x; vy += rv.y;
  }
  vx = ga.x * vx * BN_INV + be.x;
  vy = ga.y * vy * BN_INV + be.y;
  float2 o;
  o.x = vx > 0.f ? vx : __expf(vx) - 1.f;
  o.y = vy > 0.f ? vy : __expf(vy) - 1.f;
  *(float2*)&out[(size_t)n * 128 + c0] = o;
}

// -------- layer-2 aggregation (H=1, O=32), 8-edge MLP chunks, no atomics ---------

__global__ __launch_bounds__(256) void gat_agg32(const float* __restrict__ h,
    const float* __restrict__ es, const float* __restrict__ ed,
    const int* __restrict__ offs, const int* __restrict__ csr,
    const float* __restrict__ bias, float* __restrict__ h2, int Nn) {
  int n = blockIdx.x * 8 + (threadIdx.x >> 5);
  if (n >= Nn) return;
  int c = threadIdx.x & 31;
  float edn = ed[n];
  float e0 = es[n] + edn;
  e0 = e0 > 0.f ? e0 : 0.2f * e0;
  float w0 = __expf(e0);
  float den = w0;
  float acc = w0 * h[(size_t)n * 32 + c];
  int beg = offs[n], end = offs[n + 1];
  for (int base = beg; base < end; base += 8) {
    int cnt = end - base;
    int s[8];
#pragma unroll
    for (int j = 0; j < 8; ++j) s[j] = (j < cnt) ? csr[base + j] : n;
    float hv[8];
#pragma unroll
    for (int j = 0; j < 8; ++j) hv[j] = h[(size_t)s[j] * 32 + c];
    float w[8];
#pragma unroll
    for (int j = 0; j < 8; ++j) {
      float e = es[s[j]] + edn;
      e = e > 0.f ? e : 0.2f * e;
      w[j] = (j < cnt) ? __expf(e) : 0.f;
    }
#pragma unroll
    for (int j = 0; j < 8; ++j) {
      den += w[j];
      acc += w[j] * hv[j];
    }
  }
  h2[(size_t)n * 32 + c] = acc / (den + 1e-16f) + bias[c];
}

// -------- head: mean-pool (sorted-batch range), conv1d x2, MLP, log_softmax ------

__global__ __launch_bounds__(256) void head_kernel(const float* __restrict__ h2,
    const int* __restrict__ batch,
    const float* __restrict__ c0w, const float* __restrict__ c0b,
    const float* __restrict__ cg0, const float* __restrict__ cb0,
    const float* __restrict__ c1w, const float* __restrict__ c1b,
    const float* __restrict__ l1w, const float* __restrict__ l1b,
    const float* __restrict__ l2w, const float* __restrict__ l2b,
    float* __restrict__ out) {
  int b = blockIdx.x;
  int t = threadIdx.x;
  __shared__ float sums[8][32];
  __shared__ float pooled[32];
  __shared__ float z1[32][32];
  __shared__ float z2[16][32];
  __shared__ float emb[16];
  __shared__ float hfc[8];
  __shared__ float logits[10];

  int lo = 0, hi = NNODES;
  while (lo < hi) { int mid = (lo + hi) >> 1; if (batch[mid] < b) lo = mid + 1; else hi = mid; }
  int start = lo;
  lo = 0; hi = NNODES;
  while (lo < hi) { int mid = (lo + hi) >> 1; if (batch[mid] < b + 1) lo = mid + 1; else hi = mid; }
  int end = lo;

  {
    int ch = t & 31, g = t >> 5;
    float s = 0.f;
    for (int i = start + g; i < end; i += 8) s += h2[(size_t)i * 32 + ch];
    sums[g][ch] = s;
  }
  __syncthreads();
  if (t < 32) {
    float s = 0.f;
#pragma unroll
    for (int g = 0; g < 8; ++g) s += sums[g][t];
    float cn = fmaxf((float)(end - start), 1.0f);
    pooled[t] = s / cn;
  }
  __syncthreads();
  for (int i = t; i < 1024; i += 256) {
    int oc = i >> 5, tt = i & 31;
    float a = c0b[oc];
#pragma unroll
    for (int k = 0; k < 5; ++k) {
      int p = tt + k - 2;
      if (p >= 0 && p < 32) a += pooled[p] * c0w[oc * 5 + k];
    }
    a = cg0[oc] * a * BN_INV + cb0[oc];
    z1[oc][tt] = a > 0.f ? a : __expf(a) - 1.f;
  }
  __syncthreads();
  for (int i = t; i < 512; i += 256) {
    int oc = i >> 5, tt = i & 31;
    float a = c1b[oc];
    for (int ic = 0; ic < 32; ++ic) {
      const float* wrow = &c1w[(oc * 32 + ic) * 5];
#pragma unroll
      for (int k = 0; k < 5; ++k) {
        int p = tt + k - 2;
        if (p >= 0 && p < 32) a += z1[ic][p] * wrow[k];
      }
    }
    z2[oc][tt] = a;
  }
  __syncthreads();
  if (t < 16) {
    float s = 0.f;
    for (int i = 0; i < 32; ++i) s += z2[t][i];
    s *= (1.0f / 32.0f);
    emb[t] = s;
    out[640 + b * 16 + t] = s;     // output 1: embed (64 x 16)
  }
  __syncthreads();
  if (t < 8) {
    float a = l1b[t];
    for (int i = 0; i < 16; ++i) a += emb[i] * l1w[i * 8 + t];
    hfc[t] = a > 0.f ? a : __expf(a) - 1.f;
  }
  __syncthreads();
  if (t < 10) {
    float a = l2b[t];
    for (int j = 0; j < 8; ++j) a += hfc[j] * l2w[j * 10 + t];
    logits[t] = a;
  }
  __syncthreads();
  if (t == 0) {
    float m = logits[0];
    for (int k = 1; k < 10; ++k) m = fmaxf(m, logits[k]);
    float s = 0.f;
    for (int k = 0; k < 10; ++k) s += __expf(logits[k] - m);
    float lse = m + logf(s);
    for (int k = 0; k < 10; ++k) out[b * 10 + k] = logits[k] - lse;  // output 0
  }
}

// ---------------- launch ----------------

extern "C" void kernel_launch(void* const* d_in, const int* in_sizes, int n_in,
                              void* d_out, int out_size, void* d_ws, size_t ws_size,
                              hipStream_t stream) {
  const float* x   = (const float*)d_in[0];
  const int* eidx  = (const int*)d_in[1];
  const int* esrc  = eidx;
  const int* edst  = eidx + NEDGES;
  const int* batch = (const int*)d_in[2];
  const float* W0  = (const float*)d_in[3];
  const float* a0s = (const float*)d_in[4];
  const float* a0d = (const float*)d_in[5];
  const float* b0  = (const float*)d_in[6];
  const float* W1  = (const float*)d_in[7];
  const float* a1s = (const float*)d_in[8];
  const float* a1d = (const float*)d_in[9];
  const float* b1  = (const float*)d_in[10];
  const float* W2  = (const float*)d_in[11];
  const float* a2s = (const float*)d_in[12];
  const float* a2d = (const float*)d_in[13];
  const float* b2  = (const float*)d_in[14];
  const float* g0  = (const float*)d_in[15];
  const float* be0 = (const float*)d_in[16];
  const float* g1  = (const float*)d_in[17];
  const float* be1 = (const float*)d_in[18];
  const float* c0w = (const float*)d_in[19];
  const float* c0b = (const float*)d_in[20];
  const float* cg0 = (const float*)d_in[21];
  const float* cb0 = (const float*)d_in[22];
  const float* c1w = (const float*)d_in[23];
  const float* c1b = (const float*)d_in[24];
  const float* l1w = (const float*)d_in[25];
  const float* l1b = (const float*)d_in[26];
  const float* l2w = (const float*)d_in[27];
  const float* l2b = (const float*)d_in[28];

  char* ws = (char*)d_ws;
  int*   deg    = (int*)(ws + 0);
  int*   cursor = (int*)(ws + 208448);
  int*   offs   = (int*)(ws + 408448);
  float* es     = (float*)(ws + 608512);
  float* ed     = (float*)(ws + 1408512);
  int*   csr    = (int*)(ws + 2208512);
  float* hA     = (float*)(ws + 5408512);
  float* act0   = (float*)(ws + 31008512);
  float* act1   = (float*)(ws + 56608512);
  float* h2     = act0;              // act0 free after layer-1 agg
  float* out    = (float*)d_out;

  hipMemsetAsync(d_ws, 0, 200000, stream);

  count_deg<<<(NEDGES + 255) / 256, 256, 0, stream>>>(edst, deg, NEDGES);
  scan_kernel<<<1, 1024, 0, stream>>>(deg, offs, cursor, NNODES);
  fill_csr<<<(NEDGES + 255) / 256, 256, 0, stream>>>(esrc, edst, cursor, csr, NEDGES);

  const int gemm_grid = (NNODES + 31) / 32;

  // --- layer 0 ---
  gemm_attn<128, 4><<<gemm_grid, 256, 0, stream>>>(x, W0, a0s, a0d, hA, es, ed, NNODES);
  gat_agg128<false><<<(NNODES + 3) / 4, 256, 0, stream>>>(hA, es, ed, offs, csr, b0, g0, be0, nullptr, act0, NNODES);

  // --- layer 1 (residual) ---
  gemm_attn<128, 4><<<gemm_grid, 256, 0, stream>>>(act0, W1, a1s, a1d, hA, es, ed, NNODES);
  gat_agg128<true><<<(NNODES + 3) / 4, 256, 0, stream>>>(hA, es, ed, offs, csr, b1, g1, be1, act0, act1, NNODES);

  // --- layer 2 (H=1, O=32) ---
  gemm_attn<32, 1><<<gemm_grid, 256, 0, stream>>>(act1, W2, a2s, a2d, hA, es, ed, NNODES);
  gat_agg32<<<(NNODES + 7) / 8, 256, 0, stream>>>(hA, es, ed, offs, csr, b2, h2, NNODES);

  // --- head (pool fused) ---
  head_kernel<<<64, 256, 0, stream>>>(h2, batch, c0w, c0b, cg0, cb0,
                                      c1w, c1b, l1w, l1b, l2w, l2b, out);
}